// Round 1
// baseline (2876.324 us; speedup 1.0000x reference)
//
#include <hip/hip_runtime.h>

// ============================================================================
// PerceiverEncoder forward, MI355X (gfx950).
//   B=8, M=4096, C=512 input tokens; N=512 latents, D=1024, H=8 (hd=128),
//   DD=4096 MLP hidden, L=6 self-attn layers. Output fp32 [8,512,1024].
// Strategy: bf16 MFMA for all matmuls (fp32 accum), fp32 residual stream/LN/
// softmax. Weights transposed+converted per call (re-poison-safe).
// Workspace: ~305 MiB.
// ============================================================================

typedef short  short8  __attribute__((ext_vector_type(8)));   // 8 x bf16 bits
typedef unsigned short ushort8v __attribute__((ext_vector_type(8)));
typedef float  f32x4   __attribute__((ext_vector_type(4)));

__device__ __forceinline__ unsigned short f2bf(float f) {     // RNE fp32->bf16
  unsigned int u = __builtin_bit_cast(unsigned int, f);
  u += 0x7FFFu + ((u >> 16) & 1u);
  return (unsigned short)(u >> 16);
}

__device__ __forceinline__ void async16(const void* g, void* l) {
  __builtin_amdgcn_global_load_lds(
      (const __attribute__((address_space(1))) unsigned int*)g,
      (__attribute__((address_space(3))) unsigned int*)l, 16, 0, 0);
}

__device__ __forceinline__ f32x4 mfma_bf16(short8 a, short8 b, f32x4 c) {
  return __builtin_amdgcn_mfma_f32_16x16x32_bf16(a, b, c, 0, 0, 0);
}

// ---------------------------------------------------------------------------
// GEMM: C[M,N] = A[M,K](bf16) @ Bt[N,K](bf16)^T  + bias, epilogue variants.
// MODE 0: +bias -> bf16 out.  MODE 1: +bias, exact GELU -> bf16 out.
// MODE 2: +bias + resid(fp32) -> fp32 out.
// Requires M%128==0, N%128==0, K%64==0. m97 structure: 128x128 tile, BK=64,
// 256 threads (4 waves, 2x2), global_load_lds staging, 16x16x32 bf16 MFMA.
// ---------------------------------------------------------------------------
template <int MODE>
__global__ __launch_bounds__(256)
void gemm_bt(const unsigned short* __restrict__ A,
             const unsigned short* __restrict__ Bt,
             const float* __restrict__ bias,
             const float* __restrict__ resid,
             void* __restrict__ Cp,
             int M, int N, int K)
{
  __shared__ unsigned short As[128 * 64];
  __shared__ unsigned short Bs[128 * 64];
  const int tid = (int)threadIdx.x;
  const int w = tid >> 6, l = tid & 63, g = l >> 4, p = l & 15;
  const int wr = w >> 1, wc = w & 1;
  const long brow = (long)blockIdx.y * 128;
  const long bcol = (long)blockIdx.x * 128;
  const int crow = l >> 3;            // chunk-local row (8 rows / 1KB chunk)
  const int ccol = (l & 7) * 8;       // elems within row

  f32x4 acc[4][4] = {};

  for (int k0 = 0; k0 < K; k0 += 64) {
    __syncthreads();                   // prior readers done
#pragma unroll
    for (int i = 0; i < 4; ++i) {
      const int ch = w * 4 + i;        // 16 x 1KB chunks per tile
      const long rA = brow + ch * 8 + crow;
      async16(A + rA * (long)K + k0 + ccol, (char*)As + ch * 1024);
      const long rB = bcol + ch * 8 + crow;
      async16(Bt + rB * (long)K + k0 + ccol, (char*)Bs + ch * 1024);
    }
    __syncthreads();                   // vmcnt(0) drain -> data visible
#pragma unroll
    for (int ks = 0; ks < 2; ++ks) {
      short8 af[4], bfr[4];
#pragma unroll
      for (int m = 0; m < 4; ++m) {
        const int row = wr * 64 + m * 16 + p;
        af[m] = *(const short8*)((const char*)As + row * 128 + ks * 64 + g * 16);
      }
#pragma unroll
      for (int n = 0; n < 4; ++n) {
        const int row = wc * 64 + n * 16 + p;
        bfr[n] = *(const short8*)((const char*)Bs + row * 128 + ks * 64 + g * 16);
      }
#pragma unroll
      for (int m = 0; m < 4; ++m)
#pragma unroll
        for (int n = 0; n < 4; ++n)
          acc[m][n] = mfma_bf16(af[m], bfr[n], acc[m][n]);
    }
  }

  // epilogue: C[row][col], row = 4*(l>>4)+r within 16x16 frag, col = l&15
#pragma unroll
  for (int n = 0; n < 4; ++n) {
    const long col = bcol + wc * 64 + n * 16 + p;
    const float bv = bias[col];
#pragma unroll
    for (int m = 0; m < 4; ++m) {
      const long row0 = brow + wr * 64 + m * 16 + g * 4;
#pragma unroll
      for (int r = 0; r < 4; ++r) {
        float v = acc[m][n][r] + bv;
        const long off = (row0 + r) * (long)N + col;
        if constexpr (MODE == 1)
          v = 0.5f * v * (1.0f + erff(v * 0.70710678118654752f));
        if constexpr (MODE == 2)
          ((float*)Cp)[off] = v + resid[off];
        else
          ((unsigned short*)Cp)[off] = f2bf(v);
      }
    }
  }
}

// ---------------------------------------------------------------------------
// Flash attention. Grid (Nq/64, B*H), 256 threads (4 waves x 16 queries).
// Swapped operands: S^T = K-tile(64x128) * Q^T -> softmax rows lane-local.
// Q bf16 [B?,512,1024] (qBatchStride elems; 0 => shared across batch)
// K bf16 [B,Mk,1024] row-major;  Vt bf16 [B,1024,Mk] (V transposed per batch)
// O bf16 [B,512,1024]. c1 = head_scale * log2(e).
// K/V LDS tiles staged via global_load_lds with XOR swizzle (src-side).
// ---------------------------------------------------------------------------
__global__ __launch_bounds__(256)
void flash_attn(const unsigned short* __restrict__ Q,
                const unsigned short* __restrict__ Kp,
                const unsigned short* __restrict__ Vt,
                unsigned short* __restrict__ O,
                int Mk, long qBatchStride, float c1)
{
  __shared__ unsigned short Ks[64 * 128];   // [64 keys][128 c]  16KB
  __shared__ unsigned short Vs[128 * 64];   // [128 c][64 keys]  16KB
  const int tid = (int)threadIdx.x;
  const int w = tid >> 6, l = tid & 63, g = l >> 4, p = l & 15;
  const int b = (int)blockIdx.y >> 3, h = (int)blockIdx.y & 7;
  const int q0 = (int)blockIdx.x * 64 + w * 16;   // this wave's 16 queries

  // Q fragments (B-operand), kept in registers: Q[q0+p][h*128 + ks*32+g*8+j]
  const unsigned short* qptr =
      Q + (long)b * qBatchStride + (long)(q0 + p) * 1024 + h * 128 + g * 8;
  short8 qf[4];
#pragma unroll
  for (int ks = 0; ks < 4; ++ks) qf[ks] = *(const short8*)(qptr + ks * 32);

  const unsigned short* Kb = Kp + (long)b * Mk * 1024 + h * 128;
  const unsigned short* Vb = Vt + ((long)b * 1024 + h * 128) * (long)Mk;

  f32x4 oacc[8] = {};
  float m_run = -3.0e38f, l_run = 0.0f;

  for (int kt = 0; kt < Mk; kt += 64) {
    __syncthreads();
#pragma unroll
    for (int i = 0; i < 4; ++i) {
      const int ch = w * 4 + i;
      {  // K tile: 4 rows per 1KB chunk, row stride 256B, swizzled source
        const int tr = ch * 4 + (l >> 4);
        const int cb = ((l & 15) * 16) ^ ((tr & 7) << 4);
        async16(Kb + (long)(kt + tr) * 1024 + (cb >> 1), (char*)Ks + ch * 1024);
      }
      {  // V^T tile: 8 rows per chunk, row stride 128B
        const int tr = ch * 8 + (l >> 3);
        const int cb = ((l & 7) * 16) ^ ((tr & 7) << 4);
        async16(Vb + (long)tr * Mk + kt + (cb >> 1), (char*)Vs + ch * 1024);
      }
    }
    __syncthreads();

    // S^T = K * Q^T : acc[s][r] = S^T[key = s*16+4g+r][query = p]
    f32x4 sacc[4] = {};
#pragma unroll
    for (int ks = 0; ks < 4; ++ks)
#pragma unroll
      for (int s = 0; s < 4; ++s) {
        const int row = s * 16 + p;
        const int cb = (ks * 64 + g * 16) ^ ((row & 7) << 4);
        const short8 kf = *(const short8*)((const char*)Ks + row * 256 + cb);
        sacc[s] = mfma_bf16(kf, qf[ks], sacc[s]);
      }

    // online softmax (per query p; 16 vals/lane + 2 xor steps across groups)
    float mt = -3.0e38f;
#pragma unroll
    for (int s = 0; s < 4; ++s)
#pragma unroll
      for (int r = 0; r < 4; ++r) mt = fmaxf(mt, sacc[s][r]);
    mt = fmaxf(mt, __shfl_xor(mt, 16));
    mt = fmaxf(mt, __shfl_xor(mt, 32));
    const float m_new = fmaxf(m_run, mt);
    const float corr = exp2f((m_run - m_new) * c1);
    float P[4][4];
    float ls = 0.0f;
#pragma unroll
    for (int s = 0; s < 4; ++s)
#pragma unroll
      for (int r = 0; r < 4; ++r) {
        const float e = exp2f((sacc[s][r] - m_new) * c1);
        P[s][r] = e; ls += e;
      }
    ls += __shfl_xor(ls, 16);
    ls += __shfl_xor(ls, 32);
    l_run = l_run * corr + ls;
    m_run = m_new;
#pragma unroll
    for (int t = 0; t < 8; ++t)
#pragma unroll
      for (int r = 0; r < 4; ++r) oacc[t][r] *= corr;

    // redistribute P (C-layout) -> PV B-fragments via bpermute
    // dest lane (g,p), slice ks2, slot jj: key = ks2*32+8g+jj held by
    // lane ((2*(g&1))+(jj>>2))*16+p in reg P[2*ks2+(g>>1)][jj&3]
    float pf[2][8];
#pragma unroll
    for (int s = 0; s < 4; ++s)
#pragma unroll
      for (int r = 0; r < 4; ++r)
#pragma unroll
        for (int hf = 0; hf < 2; ++hf) {
          const float tv = __shfl(P[s][r], ((g & 1) * 2 + hf) * 16 + p);
          if ((g >> 1) == (s & 1)) pf[s >> 1][(hf << 2) | r] = tv;
        }
    short8 pb[2];
#pragma unroll
    for (int ks2 = 0; ks2 < 2; ++ks2) {
      ushort8v t8;
#pragma unroll
      for (int jj = 0; jj < 8; ++jj) t8[jj] = f2bf(pf[ks2][jj]);
      pb[ks2] = __builtin_bit_cast(short8, t8);
    }

    // O^T += V^T * P^T : oacc[t][r] = O^T[c = t*16+4g+r][query = p]
#pragma unroll
    for (int ks2 = 0; ks2 < 2; ++ks2)
#pragma unroll
      for (int t = 0; t < 8; ++t) {
        const int row = t * 16 + p;
        const int cb = (ks2 * 64 + g * 16) ^ ((row & 7) << 4);
        const short8 vf = *(const short8*)((const char*)Vs + row * 128 + cb);
        oacc[t] = mfma_bf16(vf, pb[ks2], oacc[t]);
      }
  }

  __syncthreads();   // everyone done with Ks/Vs; reuse Ks for O transpose
  const float inv = 1.0f / l_run;
  char* om = (char*)Ks + w * 4096;   // per-wave [16 q][128 c] bf16, swizzled
#pragma unroll
  for (int t = 0; t < 8; ++t) {
    const int cbase = t * 32 + g * 8;   // byte col of elems t*16+4g..+3
    const int off = p * 256 + (cbase ^ ((p & 7) << 4));
    uint2 pk;
    pk.x = (unsigned int)f2bf(oacc[t][0] * inv) |
           ((unsigned int)f2bf(oacc[t][1] * inv) << 16);
    pk.y = (unsigned int)f2bf(oacc[t][2] * inv) |
           ((unsigned int)f2bf(oacc[t][3] * inv) << 16);
    *(uint2*)(om + off) = pk;
  }
  const int q = l >> 2;
  const int chb0 = (l & 3) * 64;
  unsigned short* obase =
      O + ((long)b * 512 + q0 + q) * 1024 + h * 128 + (chb0 >> 1);
#pragma unroll
  for (int i = 0; i < 4; ++i) {
    const int off = q * 256 + ((chb0 + i * 16) ^ ((q & 7) << 4));
    const short8 vv = *(const short8*)(om + off);
    *(short8*)(obase + i * 8) = vv;
  }
}

// ---------------------------------------------------------------------------
// LayerNorm: fp32 [rows, cols] -> bf16, cols in {512,1024}, eps 1e-5.
// ---------------------------------------------------------------------------
__global__ __launch_bounds__(256)
void ln_kernel(const float* __restrict__ x, const float* __restrict__ gw,
               const float* __restrict__ gb, unsigned short* __restrict__ y,
               int cols)
{
  const long row = blockIdx.x;
  const float* xr = x + row * (long)cols;
  unsigned short* yr = y + row * (long)cols;
  float s = 0.0f, s2 = 0.0f;
  for (int c = (int)threadIdx.x * 4; c < cols; c += 1024) {
    const float4 v = *(const float4*)(xr + c);
    s  += v.x + v.y + v.z + v.w;
    s2 += v.x * v.x + v.y * v.y + v.z * v.z + v.w * v.w;
  }
#pragma unroll
  for (int o = 32; o; o >>= 1) { s += __shfl_xor(s, o); s2 += __shfl_xor(s2, o); }
  __shared__ float rs_[4], rs2_[4];
  const int wv = (int)threadIdx.x >> 6;
  if ((threadIdx.x & 63) == 0) { rs_[wv] = s; rs2_[wv] = s2; }
  __syncthreads();
  s  = rs_[0] + rs_[1] + rs_[2] + rs_[3];
  s2 = rs2_[0] + rs2_[1] + rs2_[2] + rs2_[3];
  const float invn = 1.0f / (float)cols;
  const float mu = s * invn;
  const float var = fmaxf(s2 * invn - mu * mu, 0.0f);
  const float rstd = rsqrtf(var + 1e-5f);
  for (int c = (int)threadIdx.x * 4; c < cols; c += 1024) {
    const float4 v = *(const float4*)(xr + c);
    const float4 w4 = *(const float4*)(gw + c);
    const float4 b4 = *(const float4*)(gb + c);
    ushort4 o;
    o.x = f2bf((v.x - mu) * rstd * w4.x + b4.x);
    o.y = f2bf((v.y - mu) * rstd * w4.y + b4.y);
    o.z = f2bf((v.z - mu) * rstd * w4.z + b4.z);
    o.w = f2bf((v.w - mu) * rstd * w4.w + b4.w);
    *(ushort4*)(yr + c) = o;
  }
}

// ---------------------------------------------------------------------------
// Weight transpose+convert: fp32 [R,Cc] -> bf16 [Cc,R]. 32x32 LDS tiles.
// ---------------------------------------------------------------------------
__global__ __launch_bounds__(256)
void tw_kernel(const float* __restrict__ in, unsigned short* __restrict__ out,
               int R, int Cc)
{
  __shared__ float t[32][33];
  const int tx = (int)threadIdx.x & 31, ty = (int)threadIdx.x >> 5;
  const long c0 = (long)blockIdx.x * 32;
  const long r0 = (long)blockIdx.y * 32;
#pragma unroll
  for (int j = 0; j < 4; ++j)
    t[ty + j * 8][tx] = in[(r0 + ty + j * 8) * (long)Cc + c0 + tx];
  __syncthreads();
#pragma unroll
  for (int j = 0; j < 4; ++j)
    out[(c0 + ty + j * 8) * (long)R + r0 + tx] = f2bf(t[tx][ty + j * 8]);
}

// Batched bf16 transpose (V -> V^T per batch): [z][R,Cc] -> [z][Cc,R]
__global__ __launch_bounds__(256)
void tb_kernel(const unsigned short* __restrict__ in,
               unsigned short* __restrict__ out, int R, int Cc)
{
  __shared__ unsigned short t[32][33];
  const long zoff = (long)blockIdx.z * (long)R * Cc;
  const int tx = (int)threadIdx.x & 31, ty = (int)threadIdx.x >> 5;
  const long c0 = (long)blockIdx.x * 32;
  const long r0 = (long)blockIdx.y * 32;
#pragma unroll
  for (int j = 0; j < 4; ++j)
    t[ty + j * 8][tx] = in[zoff + (r0 + ty + j * 8) * (long)Cc + c0 + tx];
  __syncthreads();
#pragma unroll
  for (int j = 0; j < 4; ++j)
    out[zoff + (c0 + ty + j * 8) * (long)R + r0 + tx] = t[tx][ty + j * 8];
}

// latent [512*1024] -> broadcast x8 into h0 (fp32)
__global__ __launch_bounds__(256)
void bcast_kernel(const float* __restrict__ in, float* __restrict__ out)
{
  const int i = (int)(blockIdx.x * 256 + threadIdx.x);   // float4 index
  ((float4*)out)[i] = ((const float4*)in)[i & 131071];   // 131072 = 512*1024/4
}

// ---------------------------------------------------------------------------
extern "C" void kernel_launch(void* const* d_in, const int* in_sizes, int n_in,
                              void* d_out, int out_size, void* d_ws,
                              size_t ws_size, hipStream_t stream)
{
  (void)in_sizes; (void)n_in; (void)out_size; (void)ws_size;
  const int Bx = 8, Mx = 4096, Cx = 512, Nx = 512, Dx = 1024, DDx = 4096, Lx = 6;
  const int TN = Bx * Nx;     // 4096 latent tokens
  const int TM = Bx * Mx;     // 32768 input tokens
  const float c1 = 0.08838834764831845f * 1.44269504088896340f; // scale*log2e

  const float* x      = (const float*)d_in[0];
  const float* latent = (const float*)d_in[1];
  const float* ca_qn_w = (const float*)d_in[2];
  const float* ca_qn_b = (const float*)d_in[3];
  const float* ca_kvn_w = (const float*)d_in[4];
  const float* ca_kvn_b = (const float*)d_in[5];
  const float* ca_wq = (const float*)d_in[6];
  const float* ca_bq = (const float*)d_in[7];
  const float* ca_wk = (const float*)d_in[8];
  const float* ca_bk = (const float*)d_in[9];
  const float* ca_wv = (const float*)d_in[10];
  const float* ca_bv = (const float*)d_in[11];
  const float* ca_wo = (const float*)d_in[12];
  const float* ca_bo = (const float*)d_in[13];
  const float* ca_ln_w = (const float*)d_in[14];
  const float* ca_ln_b = (const float*)d_in[15];
  const float* ca_w1 = (const float*)d_in[16];
  const float* ca_b1 = (const float*)d_in[17];
  const float* ca_w2 = (const float*)d_in[18];
  const float* ca_b2 = (const float*)d_in[19];
  const float* sa_n_w = (const float*)d_in[20];
  const float* sa_n_b = (const float*)d_in[21];
  const float* sa_wq = (const float*)d_in[22];
  const float* sa_bq = (const float*)d_in[23];
  const float* sa_wk = (const float*)d_in[24];
  const float* sa_bk = (const float*)d_in[25];
  const float* sa_wv = (const float*)d_in[26];
  const float* sa_bv = (const float*)d_in[27];
  const float* sa_wo = (const float*)d_in[28];
  const float* sa_bo = (const float*)d_in[29];
  const float* sa_ln_w = (const float*)d_in[30];
  const float* sa_ln_b = (const float*)d_in[31];
  const float* sa_w1 = (const float*)d_in[32];
  const float* sa_b1 = (const float*)d_in[33];
  const float* sa_w2 = (const float*)d_in[34];
  const float* sa_b2 = (const float*)d_in[35];

  char* wp = (char*)d_ws;
  auto alloc = [&](size_t bytes) {
    char* r = wp; wp += (bytes + 255) & ~(size_t)255; return r;
  };
  float* hA = (float*)alloc((size_t)TN * Dx * 4);          // residual ping
  float* hB = (float*)alloc((size_t)TN * Dx * 4);          // residual pong
  unsigned short* lnb  = (unsigned short*)alloc((size_t)TN * Dx * 2);
  unsigned short* qb   = (unsigned short*)alloc((size_t)TN * Dx * 2);
  unsigned short* ob   = (unsigned short*)alloc((size_t)TN * Dx * 2);
  unsigned short* mlpb = (unsigned short*)alloc((size_t)TN * DDx * 2); // also x_ln
  unsigned short* Kb   = (unsigned short*)alloc((size_t)TM * Dx * 2);
  unsigned short* Vb   = (unsigned short*)alloc((size_t)TM * Dx * 2);
  unsigned short* VTb  = (unsigned short*)alloc((size_t)TM * Dx * 2);
  unsigned short* wtq  = (unsigned short*)alloc((size_t)Dx * Dx * 2);
  unsigned short* wtk  = (unsigned short*)alloc((size_t)Dx * Dx * 2);
  unsigned short* wtv  = (unsigned short*)alloc((size_t)Dx * Dx * 2);
  unsigned short* wto  = (unsigned short*)alloc((size_t)Dx * Dx * 2);
  unsigned short* wtm1 = (unsigned short*)alloc((size_t)Dx * DDx * 2);
  unsigned short* wtm2 = (unsigned short*)alloc((size_t)Dx * DDx * 2);

  const dim3 blk(256);
  auto TW = [&](const float* win, unsigned short* wout, int R, int Cc) {
    tw_kernel<<<dim3(Cc / 32, R / 32), blk, 0, stream>>>(win, wout, R, Cc);
  };
  auto LN = [&](const float* xin, const float* gw, const float* gb,
                unsigned short* y, int rows, int cols) {
    ln_kernel<<<dim3(rows), blk, 0, stream>>>(xin, gw, gb, y, cols);
  };
  auto G0 = [&](const unsigned short* A, const unsigned short* Bt2,
                const float* bias, unsigned short* out, int M2, int N2, int K2) {
    gemm_bt<0><<<dim3(N2 / 128, M2 / 128), blk, 0, stream>>>(
        A, Bt2, bias, nullptr, out, M2, N2, K2);
  };
  auto G1 = [&](const unsigned short* A, const unsigned short* Bt2,
                const float* bias, unsigned short* out, int M2, int N2, int K2) {
    gemm_bt<1><<<dim3(N2 / 128, M2 / 128), blk, 0, stream>>>(
        A, Bt2, bias, nullptr, out, M2, N2, K2);
  };
  auto G2 = [&](const unsigned short* A, const unsigned short* Bt2,
                const float* bias, const float* resid, float* out,
                int M2, int N2, int K2) {
    gemm_bt<2><<<dim3(N2 / 128, M2 / 128), blk, 0, stream>>>(
        A, Bt2, bias, resid, out, M2, N2, K2);
  };

  // ---------------- cross-attention block ----------------
  bcast_kernel<<<dim3(TN * Dx / 4 / 256), blk, 0, stream>>>(latent, hA);
  LN(latent, ca_qn_w, ca_qn_b, lnb, Nx, Dx);              // LN(lat) [512,1024]
  TW(ca_wq, wtq, Dx, Dx);
  G0(lnb, wtq, ca_bq, qb, Nx, Dx, Dx);                    // q (shared over b)
  LN(x, ca_kvn_w, ca_kvn_b, mlpb, TM, Cx);                // x_ln [32768,512]
  TW(ca_wk, wtk, Cx, Dx);
  G0(mlpb, wtk, ca_bk, Kb, TM, Dx, Cx);                   // K [32768,1024]
  TW(ca_wv, wtv, Cx, Dx);
  G0(mlpb, wtv, ca_bv, Vb, TM, Dx, Cx);                   // V
  tb_kernel<<<dim3(Dx / 32, Mx / 32, Bx), blk, 0, stream>>>(Vb, VTb, Mx, Dx);
  flash_attn<<<dim3(Nx / 64, Bx * 8), blk, 0, stream>>>(
      qb, Kb, VTb, ob, Mx, 0L, c1);
  TW(ca_wo, wto, Dx, Dx);
  G2(ob, wto, ca_bo, hA, hB, TN, Dx, Dx);                 // +lat residual
  LN(hB, ca_ln_w, ca_ln_b, lnb, TN, Dx);
  TW(ca_w1, wtm1, Dx, DDx);
  G1(lnb, wtm1, ca_b1, mlpb, TN, DDx, Dx);                // GELU
  TW(ca_w2, wtm2, DDx, Dx);
  G2(mlpb, wtm2, ca_b2, hB, hA, TN, Dx, DDx);             // h back in hA

  // ---------------- 6 self-attention layers ----------------
  for (int i = 0; i < Lx; ++i) {
    LN(hA, sa_n_w + (size_t)i * Dx, sa_n_b + (size_t)i * Dx, lnb, TN, Dx);
    TW(sa_wq + (size_t)i * Dx * Dx, wtq, Dx, Dx);
    G0(lnb, wtq, sa_bq + (size_t)i * Dx, qb, TN, Dx, Dx);
    TW(sa_wk + (size_t)i * Dx * Dx, wtk, Dx, Dx);
    G0(lnb, wtk, sa_bk + (size_t)i * Dx, Kb, TN, Dx, Dx);
    TW(sa_wv + (size_t)i * Dx * Dx, wtv, Dx, Dx);
    G0(lnb, wtv, sa_bv + (size_t)i * Dx, Vb, TN, Dx, Dx);
    tb_kernel<<<dim3(Dx / 32, Nx / 32, Bx), blk, 0, stream>>>(Vb, VTb, Nx, Dx);
    flash_attn<<<dim3(Nx / 64, Bx * 8), blk, 0, stream>>>(
        qb, Kb, VTb, ob, Nx, (long)Nx * Dx, c1);
    TW(sa_wo + (size_t)i * Dx * Dx, wto, Dx, Dx);
    G2(ob, wto, sa_bo + (size_t)i * Dx, hA, hB, TN, Dx, Dx);
    LN(hB, sa_ln_w + (size_t)i * Dx, sa_ln_b + (size_t)i * Dx, lnb, TN, Dx);
    TW(sa_w1 + (size_t)i * Dx * DDx, wtm1, Dx, DDx);
    G1(lnb, wtm1, sa_b1 + (size_t)i * DDx, mlpb, TN, DDx, Dx);
    TW(sa_w2 + (size_t)i * DDx * Dx, wtm2, DDx, Dx);
    float* outp = (i == Lx - 1) ? (float*)d_out : hA;
    G2(mlpb, wtm2, sa_b2 + (size_t)i * Dx, hB, outp, TN, Dx, DDx);
  }
}